// Round 8
// baseline (72.297 us; speedup 1.0000x reference)
//
#include <hip/hip_runtime.h>
#include <float.h>
#include <math.h>

// Problem constants (fixed by reference)
#define NB    8
#define K1    2048
#define K2    8192
#define NADD  16
#define PP    128          // K1 / NUM_ADD
#define FEPS  1e-7f
#define CDW   0.1f

// chamfer tiling -- R3's empirical best config
#define OCH   64           // ori chunks
#define OCLEN (K2 / OCH)   // 128 ori points per chunk
#define KC    2            // adv halves
#define MPT   4            // adv points per thread: 4 independent min chains
#define FAR_GRID 64                   // farthest blocks (first)
#define CH_GRID  (OCH * KC * NB)      // 1024 chamfer blocks
#define TOT_GRID (FAR_GRID + CH_GRID) // 1088
#define RED_GRID 64                   // last-64 arrivals do the reduce

// ws layout (32-bit word offsets)
#define CTR_IDX  0                    // [0]=ctr, [1]=ctr2  (memset to 0 each call)
#define FARW_IDX 4                    // 128 floats
#define CHB_IDX  (FARW_IDX + NB * NADD)   // 64 floats
#define PMIN_IDX 256                  // 1,048,576 floats (4 MB)

// ---------------------------------------------------------------------------
// Single kernel.
//   blocks [0, 64)        : farthest pairwise dist per (b, cluster-pair)
//   blocks [64, 1088)     : chamfer partial min for (oc, kc, b) -> pmins
//   last 64 arrivals      : spin until all arrived, reduce one (b,kc) slice
//   last reduce arrival   : final weighted combine -> out[0]
// Cross-block visibility: each block's stores are drained by __syncthreads,
// then published by its ACQ_REL RMW on ctr; readers acquire via the ctr spin
// (release-sequence of RMWs) -- same pattern chbp has used since R3.
// ---------------------------------------------------------------------------
__global__ __launch_bounds__(256) void fused_all(const float* __restrict__ adv,
                                                 const float* __restrict__ ori,
                                                 const float* __restrict__ w,
                                                 unsigned int* __restrict__ wsw,
                                                 float* __restrict__ out) {
    __shared__ float4 s4[192];        // chamfer: 128 float4 | farthest: 768 floats
    __shared__ float sred[4];
    __shared__ unsigned int sOrd, sLast;
    unsigned int* ctr  = wsw + CTR_IDX;
    unsigned int* ctr2 = ctr + 1;
    float* far   = (float*)(wsw + FARW_IDX);
    float* chbp  = (float*)(wsw + CHB_IDX);
    float* pmins = (float*)(wsw + PMIN_IDX);
    const int bid = blockIdx.x;
    const int t   = threadIdx.x;

    if (bid < FAR_GRID) {
        // ---- farthest: block = (b, cluster-pair), 128 threads per cluster ----
        const int b  = bid >> 3;
        const int cp = bid & 7;
        const int g  = t >> 7;        // which cluster of the pair
        const int p  = t & 127;
        const int ci = cp * 2 + g;

        float* sf = (float*)s4;       // [2][3][128]
        const float* c = adv + (size_t)(b * K1 + ci * PP) * 3;
        float px = c[p * 3 + 0], py = c[p * 3 + 1], pz = c[p * 3 + 2];
        float* sx = sf + g * 384;
        sx[p] = px; sx[128 + p] = py; sx[256 + p] = pz;
        __syncthreads();

        const float pxm = px - FEPS, pym = py - FEPS, pzm = pz - FEPS;
        float mx = 0.f;
#pragma unroll 8
        for (int q = 0; q < PP; ++q) {
            float dx = sx[q] - pxm;
            float dy = sx[128 + q] - pym;
            float dz = sx[256 + q] - pzm;
            mx = fmaxf(mx, fmaf(dx, dx, fmaf(dy, dy, dz * dz)));
        }
#pragma unroll
        for (int off = 32; off; off >>= 1) mx = fmaxf(mx, __shfl_down(mx, off, 64));
        if ((t & 63) == 0) sred[t >> 6] = mx;
        __syncthreads();
        if (t == 0)   far[b * NADD + cp * 2 + 0] = sqrtf(fmaxf(sred[0], sred[1]));
        if (t == 128) far[b * NADD + cp * 2 + 1] = sqrtf(fmaxf(sred[2], sred[3]));
    } else {
        // ---- chamfer partial: ori chunk oc of batch b vs adv half kc ----
        const int cb = bid - FAR_GRID;
        const int oc = cb & (OCH - 1);
        const int kc = (cb >> 6) & (KC - 1);
        const int b  = cb >> 7;

        if (t < OCLEN) {               // stage + pack [x,y,z,|o|^2]
            const float* o = ori + ((size_t)b * K2 + oc * OCLEN + t) * 3;
            float x = o[0], y = o[1], z = o[2];
            s4[t] = make_float4(x, y, z, fmaf(x, x, fmaf(y, y, z * z)));
        }

        float bx[MPT], by[MPT], bz[MPT], dmin[MPT];
        const int k0 = kc * (K1 / KC) + t;
#pragma unroll
        for (int j = 0; j < MPT; ++j) {
            const float* a = adv + (size_t)(b * K1 + k0 + 256 * j) * 3;
            bx[j] = -2.f * a[0];
            by[j] = -2.f * a[1];
            bz[j] = -2.f * a[2];
            dmin[j] = FLT_MAX;
        }
        __syncthreads();

#pragma unroll 8
        for (int m = 0; m < OCLEN; ++m) {
            float4 o = s4[m];          // uniform address -> LDS broadcast
#pragma unroll
            for (int j = 0; j < MPT; ++j)
                dmin[j] = fminf(dmin[j],
                                fmaf(bx[j], o.x, fmaf(by[j], o.y, fmaf(bz[j], o.z, o.w))));
        }

#pragma unroll
        for (int j = 0; j < MPT; ++j)  // coalesced
            pmins[((size_t)oc * NB + b) * K1 + k0 + 256 * j] = dmin[j];
    }

    // ---- arrival; the last RED_GRID arrivals each own one reduce slice ----
    __syncthreads();                   // drains this block's stores (vmcnt 0/wave)
    if (t == 0)
        sOrd = __hip_atomic_fetch_add(ctr, 1u,
                                      __ATOMIC_ACQ_REL, __HIP_MEMORY_SCOPE_AGENT);
    __syncthreads();
    const unsigned int ord = sOrd;
    if (ord < (unsigned int)(TOT_GRID - RED_GRID)) return;
    const int slice = ord - (TOT_GRID - RED_GRID);   // 0..63

    if (t == 0) {                      // wait until every block has published
        while (__hip_atomic_load(ctr, __ATOMIC_ACQUIRE, __HIP_MEMORY_SCOPE_AGENT)
               != (unsigned int)TOT_GRID)
            __builtin_amdgcn_s_sleep(2);
    }
    __syncthreads();

    // ---- reduce slice (b, kc2): min over 64 chunks + a^2 + clamp + sum ----
    const int b2  = slice >> 3;
    const int kc2 = slice & 7;
    const int k   = kc2 * 256 + t;

    float m = FLT_MAX;
#pragma unroll 8
    for (int oc = 0; oc < OCH; ++oc)   // coalesced across threads each iter
        m = fminf(m, pmins[((size_t)oc * NB + b2) * K1 + k]);

    const float* a = adv + (size_t)(b2 * K1 + k) * 3;
    float ax = a[0], ay = a[1], az = a[2];
    float a2 = fmaf(ax, ax, fmaf(ay, ay, az * az));
    float sum = fmaxf(a2 + m, 0.f);

#pragma unroll
    for (int off = 32; off; off >>= 1) sum += __shfl_down(sum, off, 64);
    if ((t & 63) == 0) sred[t >> 6] = sum;
    __syncthreads();

    if (t == 0) {
        float part = sred[0] + sred[1] + sred[2] + sred[3];
        __hip_atomic_store(&chbp[slice], part,
                           __ATOMIC_RELEASE, __HIP_MEMORY_SCOPE_AGENT);
        unsigned int old2 = __hip_atomic_fetch_add(ctr2, 1u,
                            __ATOMIC_ACQ_REL, __HIP_MEMORY_SCOPE_AGENT);
        sLast = (old2 == RED_GRID - 1) ? 1u : 0u;
    }
    __syncthreads();
    if (!sLast) return;

    // ---- final combine (single block, fixed order -> deterministic) ----
    float v = 0.f;
    if (t < 128) v = w[t >> 4] * far[t] * 0.125f;
    if (t < 64)
        v += (CDW * 0.125f / K1) * w[t >> 3] *
             __hip_atomic_load(&chbp[t], __ATOMIC_ACQUIRE, __HIP_MEMORY_SCOPE_AGENT);
#pragma unroll
    for (int off = 32; off; off >>= 1) v += __shfl_down(v, off, 64);
    __syncthreads();                  // sred reuse safety
    if ((t & 63) == 0) sred[t >> 6] = v;
    __syncthreads();
    if (t == 0) out[0] = sred[0] + sred[1] + sred[2] + sred[3];
}

// ---------------------------------------------------------------------------
extern "C" void kernel_launch(void* const* d_in, const int* in_sizes, int n_in,
                              void* d_out, int out_size, void* d_ws, size_t ws_size,
                              hipStream_t stream) {
    const float* adv = (const float*)d_in[0];
    const float* ori = (const float*)d_in[1];
    const float* w   = (const float*)d_in[2];
    unsigned int* wsw = (unsigned int*)d_ws;
    float* out = (float*)d_out;

    hipMemsetAsync(wsw + CTR_IDX, 0, 2 * sizeof(unsigned int), stream);  // ctr, ctr2
    fused_all<<<dim3(TOT_GRID), 256, 0, stream>>>(adv, ori, w, wsw, out);
}

// Round 9
// 28.621 us; speedup vs baseline: 2.5260x; 2.5260x over previous
//
#include <hip/hip_runtime.h>
#include <float.h>
#include <math.h>

// Problem constants (fixed by reference)
#define NB    8
#define K1    2048
#define K2    8192
#define NADD  16
#define PP    128          // K1 / NUM_ADD
#define FEPS  1e-7f
#define CDW   0.1f

// chamfer tiling: R3 inner loop, fewer/bigger blocks, pmins halved to 2 MB.
#define OCH   32           // ori chunks
#define OCLEN (K2 / OCH)   // 256 ori points per chunk (staged in one pass)
#define KC    2            // adv halves
#define MPT   4            // adv points per thread: 4 independent min chains
#define FAR_GRID 64                   // farthest blocks (dispatch first)
#define CH_GRID  (OCH * KC * NB)      // 512 chamfer blocks
#define GRID_A   (FAR_GRID + CH_GRID) // 576
#define RB_GRID  64                   // reduce blocks (64 returned RMWs only)

// ws layout (float offsets)
#define PMIN_OFF 0
#define PMIN_SZ  (OCH * NB * K1)          // 524,288 floats (2 MB)
#define FARW_OFF PMIN_SZ
#define CHB_OFF  (FARW_OFF + NB * NADD)
#define CTR_OFF  (CHB_OFF + RB_GRID)

// ---------------------------------------------------------------------------
// Kernel A: farthest (blocks 0..63) + chamfer-partial (blocks 64..575).
// Chamfer block = (oc, kc, b): stages 256 ori points [x,y,z,|o|^2] in LDS
// (one pass, t stages point t), then each thread scans them against its 4
// adv points (4 independent min chains; 1 uniform ds_read_b128 -> 16 VALU).
// ---------------------------------------------------------------------------
__global__ __launch_bounds__(256) void fused_a(const float* __restrict__ adv,
                                               const float* __restrict__ ori,
                                               float* __restrict__ pmins,
                                               float* __restrict__ far,
                                               unsigned int* __restrict__ ctr) {
    __shared__ float4 s4[OCLEN];      // chamfer: 256 float4 | farthest: 768 floats
    __shared__ float sred[4];
    const int bid = blockIdx.x;
    const int t   = threadIdx.x;
    if (bid == 0 && t == 0) *ctr = 0u;   // reset kernel-B counter (B runs after A)

    if (bid < FAR_GRID) {
        // ---- farthest: block = (b, cluster-pair), 128 threads per cluster ----
        const int b  = bid >> 3;
        const int cp = bid & 7;
        const int g  = t >> 7;        // which cluster of the pair
        const int p  = t & 127;
        const int ci = cp * 2 + g;

        float* sf = (float*)s4;       // [2][3][128]
        const float* c = adv + (size_t)(b * K1 + ci * PP) * 3;
        float px = c[p * 3 + 0], py = c[p * 3 + 1], pz = c[p * 3 + 2];
        float* sx = sf + g * 384;
        sx[p] = px; sx[128 + p] = py; sx[256 + p] = pz;
        __syncthreads();

        const float pxm = px - FEPS, pym = py - FEPS, pzm = pz - FEPS;
        float mx = 0.f;
#pragma unroll 8
        for (int q = 0; q < PP; ++q) {
            float dx = sx[q] - pxm;
            float dy = sx[128 + q] - pym;
            float dz = sx[256 + q] - pzm;
            mx = fmaxf(mx, fmaf(dx, dx, fmaf(dy, dy, dz * dz)));
        }
#pragma unroll
        for (int off = 32; off; off >>= 1) mx = fmaxf(mx, __shfl_down(mx, off, 64));
        if ((t & 63) == 0) sred[t >> 6] = mx;
        __syncthreads();
        if (t == 0)   far[b * NADD + cp * 2 + 0] = sqrtf(fmaxf(sred[0], sred[1]));
        if (t == 128) far[b * NADD + cp * 2 + 1] = sqrtf(fmaxf(sred[2], sred[3]));
    } else {
        // ---- chamfer partial: ori chunk oc of batch b vs adv half kc ----
        const int cb = bid - FAR_GRID;
        const int oc = cb & (OCH - 1);
        const int kc = (cb >> 5) & (KC - 1);
        const int b  = cb >> 6;

        {   // stage + pack [x,y,z,|o|^2] -- one pass, 256 threads
            const float* o = ori + ((size_t)b * K2 + oc * OCLEN + t) * 3;
            float x = o[0], y = o[1], z = o[2];
            s4[t] = make_float4(x, y, z, fmaf(x, x, fmaf(y, y, z * z)));
        }

        float bx[MPT], by[MPT], bz[MPT], dmin[MPT];
        const int k0 = kc * (K1 / KC) + t;
#pragma unroll
        for (int j = 0; j < MPT; ++j) {
            const float* a = adv + (size_t)(b * K1 + k0 + 256 * j) * 3;
            bx[j] = -2.f * a[0];
            by[j] = -2.f * a[1];
            bz[j] = -2.f * a[2];
            dmin[j] = FLT_MAX;
        }
        __syncthreads();

#pragma unroll 8
        for (int m = 0; m < OCLEN; ++m) {
            float4 o = s4[m];          // uniform address -> LDS broadcast
#pragma unroll
            for (int j = 0; j < MPT; ++j)
                dmin[j] = fminf(dmin[j],
                                fmaf(bx[j], o.x, fmaf(by[j], o.y, fmaf(bz[j], o.z, o.w))));
        }

#pragma unroll
        for (int j = 0; j < MPT; ++j)  // coalesced
            pmins[((size_t)oc * NB + b) * K1 + k0 + 256 * j] = dmin[j];
    }
}

// ---------------------------------------------------------------------------
// Kernel B: min over 32 chunks + a^2 + clamp + per-(b,kc) sum; last-done
// block does the final weighted combine. grid 64 x 256 thr (64 returned RMWs).
// ---------------------------------------------------------------------------
__global__ __launch_bounds__(256) void reduce_b(const float* __restrict__ adv,
                                                const float* __restrict__ pmins,
                                                const float* __restrict__ far,
                                                const float* __restrict__ w,
                                                float* __restrict__ chbp,
                                                unsigned int* __restrict__ ctr,
                                                float* __restrict__ out) {
    __shared__ float s[4];
    __shared__ unsigned int lastflag;
    const int t  = threadIdx.x;
    const int kc = blockIdx.x & 7;
    const int b  = blockIdx.x >> 3;
    const int k  = kc * 256 + t;

    float m = FLT_MAX;
#pragma unroll 8
    for (int oc = 0; oc < OCH; ++oc)   // 32 loads, coalesced across threads
        m = fminf(m, pmins[((size_t)oc * NB + b) * K1 + k]);

    const float* a = adv + (size_t)(b * K1 + k) * 3;
    float ax = a[0], ay = a[1], az = a[2];
    float a2 = fmaf(ax, ax, fmaf(ay, ay, az * az));
    float sum = fmaxf(a2 + m, 0.f);

#pragma unroll
    for (int off = 32; off; off >>= 1) sum += __shfl_down(sum, off, 64);
    const int lane = t & 63, wid = t >> 6;
    if (lane == 0) s[wid] = sum;
    __syncthreads();

    if (t == 0) {
        float part = s[0] + s[1] + s[2] + s[3];
        __hip_atomic_store(&chbp[b * 8 + kc], part,
                           __ATOMIC_RELEASE, __HIP_MEMORY_SCOPE_AGENT);
        unsigned int old = __hip_atomic_fetch_add(ctr, 1u,
                           __ATOMIC_ACQ_REL, __HIP_MEMORY_SCOPE_AGENT);
        lastflag = (old == RB_GRID - 1) ? 1u : 0u;
    }
    __syncthreads();
    if (!lastflag) return;

    // ---- final combine (single block, fixed order -> deterministic) ----
    float v = 0.f;
    if (t < 128) v = w[t >> 4] * far[t] * 0.125f;
    if (t < 64)
        v += (CDW * 0.125f / K1) * w[t >> 3] *
             __hip_atomic_load(&chbp[t], __ATOMIC_ACQUIRE, __HIP_MEMORY_SCOPE_AGENT);
#pragma unroll
    for (int off = 32; off; off >>= 1) v += __shfl_down(v, off, 64);
    __syncthreads();                 // protect s[] reuse
    if (lane == 0) s[wid] = v;
    __syncthreads();
    if (t == 0) out[0] = s[0] + s[1] + s[2] + s[3];
}

// ---------------------------------------------------------------------------
extern "C" void kernel_launch(void* const* d_in, const int* in_sizes, int n_in,
                              void* d_out, int out_size, void* d_ws, size_t ws_size,
                              hipStream_t stream) {
    const float* adv = (const float*)d_in[0];
    const float* ori = (const float*)d_in[1];
    const float* w   = (const float*)d_in[2];
    float* ws    = (float*)d_ws;
    float* pmins = ws + PMIN_OFF;
    float* far   = ws + FARW_OFF;
    float* chbp  = ws + CHB_OFF;
    unsigned int* ctr = (unsigned int*)(ws + CTR_OFF);
    float* out   = (float*)d_out;

    fused_a<<<dim3(GRID_A), 256, 0, stream>>>(adv, ori, pmins, far, ctr);
    reduce_b<<<dim3(RB_GRID), 256, 0, stream>>>(adv, pmins, far, w, chbp, ctr, out);
}